// Round 8
// baseline (202.552 us; speedup 1.0000x reference)
//
#include <hip/hip_runtime.h>
#include <hip/hip_bf16.h>
#include <stdint.h>

typedef __attribute__((ext_vector_type(8))) _Float16 half8;
typedef __attribute__((ext_vector_type(4))) _Float16 half4;
typedef __attribute__((ext_vector_type(2))) __fp16 fp16x2;
typedef __attribute__((ext_vector_type(4))) float f32x4;
typedef __attribute__((ext_vector_type(16))) float f32x16;
typedef __attribute__((ext_vector_type(4))) float float4v;

#define DEVI static __device__ __forceinline__

constexpr int Bb = 16, Nn = 2048, Cc = 256, Dd = 256;

DEVI unsigned short f2h_bits(float f) {
  _Float16 h = (_Float16)f;
  union { _Float16 h; unsigned short u; } c;
  c.h = h;
  return c.u;
}

DEVI void gl_lds16(const void* gsrc, void* ldst) {
  __builtin_amdgcn_global_load_lds(
      (const __attribute__((address_space(1))) unsigned int*)gsrc,
      (__attribute__((address_space(3))) unsigned int*)ldst, 16, 0, 0);
}

DEVI f32x4 mfma16h(half8 a, half8 b, f32x4 c) {
  return __builtin_amdgcn_mfma_f32_16x16x32_f16(a, b, c, 0, 0, 0);
}
DEVI f32x16 mfma32h(half8 a, half8 b, f32x16 c) {
  return __builtin_amdgcn_mfma_f32_32x32x16_f16(a, b, c, 0, 0, 0);
}

DEVI unsigned int pkrtz(float a, float b) {
  union { fp16x2 h; unsigned int u; } c;
  c.h = __builtin_amdgcn_cvt_pkrtz(a, b);
  return c.u;
}

// ---------- kernel 0a: x (f32) -> xh (fp16) ----------
__global__ void k_split_x(const float* __restrict__ x, _Float16* __restrict__ xh) {
  int i = blockIdx.x * 256 + threadIdx.x;
  float4v v = reinterpret_cast<const float4v*>(x)[i];
  half4 h;
#pragma unroll
  for (int j = 0; j < 4; ++j) h[j] = (_Float16)v[j];
  reinterpret_cast<half4*>(xh)[i] = h;
}

// ---------- kernel 0b: W (f32) -> wh (fp16), [mat][d][c] ----------
__global__ void k_split_w(const float* __restrict__ wq, const float* __restrict__ wk,
                          const float* __restrict__ wv, _Float16* __restrict__ wh) {
  int i = blockIdx.x * 256 + threadIdx.x;
  int mat = i >> 16;
  int rem = i & 65535;
  const float* w = (mat == 0) ? wq : ((mat == 1) ? wk : wv);
  wh[(size_t)mat * 65536 + rem] = (_Float16)w[rem];
}

// ---------- kernel 1: QKV projection GEMM (fp16 in, f32 acc) ----------
// V output layout: vt[b][tile kt64][256 d][64 k] fp16 (32KB contiguous per KV tile
// so k_attn can read V fragments straight from L1/L2 with no LDS staging).
__global__ __launch_bounds__(256, 2) void k_qkv(
    const _Float16* __restrict__ xh, const _Float16* __restrict__ wh,
    const float* __restrict__ bq, const float* __restrict__ bk, const float* __restrict__ bv,
    _Float16* __restrict__ qout, _Float16* __restrict__ kout, _Float16* __restrict__ vt) {
  __shared__ __align__(16) unsigned short smem[17408];

  const int tid = threadIdx.x;
  const int m0 = blockIdx.x * 128;
  const int n0 = blockIdx.y * 128;
  const int mat = blockIdx.z;
  const _Float16* wmat = wh + (size_t)mat * 65536;
  const int wave = tid >> 6, lane = tid & 63;
  const int wr = wave >> 1, wc = wave & 1;
  const int l15 = lane & 15, lq = lane >> 4;

  f32x4 zero4 = {0.f, 0.f, 0.f, 0.f};
  f32x4 acc[4][4];
#pragma unroll
  for (int a = 0; a < 4; ++a)
#pragma unroll
    for (int b2 = 0; b2 < 4; ++b2) acc[a][b2] = zero4;

  char* As = (char*)smem;
  char* Bs = (char*)smem + 16384;

  for (int kc = 0; kc < 4; ++kc) {
#pragma unroll
    for (int i = 0; i < 4; ++i) {
      int p = i * 4096 + tid * 16;
      int row = p >> 7;
      int src_in_row = (p & 127) ^ ((row & 7) << 4);
      const char* g = (const char*)(xh + (size_t)(m0 + row) * Cc + kc * 64) + src_in_row;
      gl_lds16(g, As + p);
    }
#pragma unroll
    for (int i = 0; i < 4; ++i) {
      int p = i * 4096 + tid * 16;
      int row = p >> 7;
      int src_in_row = (p & 127) ^ ((row & 7) << 4);
      const char* g = (const char*)(wmat + (size_t)(n0 + row) * Cc + kc * 64) + src_in_row;
      gl_lds16(g, Bs + p);
    }
    __syncthreads();
#pragma unroll
    for (int ks = 0; ks < 2; ++ks) {
      half8 af[4], bfr[4];
#pragma unroll
      for (int mf = 0; mf < 4; ++mf) {
        int row = wr * 64 + mf * 16 + l15;
        int byte = (row * 128 + ks * 64 + lq * 16) ^ ((row & 7) << 4);
        af[mf] = *(const half8*)(As + byte);
      }
#pragma unroll
      for (int nf = 0; nf < 4; ++nf) {
        int row = wc * 64 + nf * 16 + l15;
        int byte = (row * 128 + ks * 64 + lq * 16) ^ ((row & 7) << 4);
        bfr[nf] = *(const half8*)(Bs + byte);
      }
#pragma unroll
      for (int mf = 0; mf < 4; ++mf)
#pragma unroll
        for (int nf = 0; nf < 4; ++nf) acc[mf][nf] = mfma16h(af[mf], bfr[nf], acc[mf][nf]);
    }
    __syncthreads();
  }

  const float* bias = (mat == 0) ? bq : ((mat == 1) ? bk : bv);
  if (mat < 2) {
    _Float16* oo = (mat == 0) ? qout : kout;
#pragma unroll
    for (int nf = 0; nf < 4; ++nf) {
      int col = n0 + wc * 64 + nf * 16 + l15;
      float bval = bias[col];
#pragma unroll
      for (int mf = 0; mf < 4; ++mf) {
        int grow = m0 + wr * 64 + mf * 16 + lq * 4;
#pragma unroll
        for (int r = 0; r < 4; ++r)
          oo[(size_t)(grow + r) * Dd + col] = (_Float16)(acc[mf][nf][r] + bval);
      }
    }
  } else {
    __syncthreads();
#pragma unroll
    for (int nf = 0; nf < 4; ++nf) {
      int dl = wc * 64 + nf * 16 + l15;
      float bval = bias[n0 + dl];
#pragma unroll
      for (int mf = 0; mf < 4; ++mf) {
        int nl = wr * 64 + mf * 16 + lq * 4;
#pragma unroll
        for (int r = 0; r < 4; ++r) smem[dl * 136 + nl + r] = f2h_bits(acc[mf][nf][r] + bval);
      }
    }
    __syncthreads();
    const int bbat = m0 >> 11, tok0 = m0 & 2047;
#pragma unroll
    for (int pss = 0; pss < 8; ++pss) {
      int idx = pss * 256 + tid;
      int dl = idx >> 4;
      int cu = idx & 15;
      half8 vval = *(const half8*)((const char*)smem + dl * 272 + cu * 16);
      int tt = (tok0 >> 6) + (cu >> 3);
      size_t off = (((size_t)bbat * 32 + tt) * 256 + (n0 + dl)) * 64 + (cu & 7) * 8;
      *(half8*)(vt + off) = vval;
    }
  }
}

// ---------- kernel 2: flash attention, 8 waves = 4 wq x 2 wk ----------
// K: LDS dbuf (counted vmcnt). V: direct global fragment loads (L1/L2-resident,
// issued early: batch A before staging, batch B mid-iter). Softmax: local-max
// pack + single-barrier (P, pm, psum) exchange; consumers rescale P frags by
// e^{pm-mnew} (packed fp16 mul). l fully lane-local. 3 barriers/tile.
__global__ __launch_bounds__(512, 2) void k_attn(
    const _Float16* __restrict__ qg, const _Float16* __restrict__ kin,
    const _Float16* __restrict__ vt, const int* __restrict__ vlen,
    float* __restrict__ out) {
  __shared__ __align__(16) char SMEM[83968];
  char* const Kb = SMEM;                                   // [2][32768] K dbuf
  unsigned int* const PL = (unsigned int*)(SMEM + 65536);  // [4 wq][32 kp][32 q]
  float* const MLX = (float*)(SMEM + 81920);               // [4 wq][2 wk][2][32]

  const int tid = threadIdx.x;
  const int wave = tid >> 6, lane = tid & 63;
  const int l31 = lane & 31, h = lane >> 5;
  const int wq = wave >> 1, wk = wave & 1;
  const int id = blockIdx.x;
  const int g = id & 7;
  const int j = id >> 3;
  const int b = g + 8 * (j >> 4);  // XCD g owns batches {g, g+8}
  const int q0 = (j & 15) * 128;
  const int L = vlen[b];
  const bool uni = (L == 0);
  const int Lk = uni ? Nn : L;
  const int nt = (Lk + 63) >> 6;

  const char* kbase = (const char*)(kin + (size_t)b * Nn * Dd);
  const _Float16* vtile = vt + (size_t)b * 32 * 256 * 64;
  const char* qbase = (const char*)(qg + ((size_t)b * Nn + q0) * Dd);

  auto STAGEK = [&](int buf, int t) {
    char* dst = Kb + buf * 32768;
    const int k0t = t * 64;
#pragma unroll
    for (int i = 0; i < 4; ++i) {
      int p = i * 8192 + tid * 16;
      int row = p >> 9;
      int sl = ((p & 511) >> 4) ^ (row & 31);
      gl_lds16(kbase + (size_t)(k0t + row) * 512 + (sl << 4), dst + p);
    }
  };

  // prologue: Q (64KB) through the K dbuf region -> qreg
#pragma unroll
  for (int i = 0; i < 8; ++i) {
    int p = i * 8192 + tid * 16;
    int row = p >> 9;
    int sl = ((p & 511) >> 4) ^ (row & 31);
    gl_lds16(qbase + (size_t)row * 512 + (sl << 4), Kb + p);
  }
  asm volatile("s_waitcnt vmcnt(0)" ::: "memory");
  asm volatile("s_barrier" ::: "memory");
  half8 qreg[16];
  {
    const int row = wq * 32 + l31;
#pragma unroll
    for (int kt = 0; kt < 16; ++kt) {
      int byte = row * 512 + (((kt * 2 + h) ^ (row & 31)) << 4);
      qreg[kt] = *(const half8*)(Kb + byte);
    }
  }
  asm volatile("s_waitcnt lgkmcnt(0)" ::: "memory");
  asm volatile("s_barrier" ::: "memory");
  STAGEK(0, 0);

  f32x16 acc[4];
#pragma unroll
  for (int dg = 0; dg < 4; ++dg)
#pragma unroll
    for (int r = 0; r < 16; ++r) acc[dg][r] = 0.f;
  float m = -__builtin_inff();
  float lsum = 0.f;

  for (int t = 0; t < nt; ++t) {
    const int cur = t & 1;
    const _Float16* vt_t = vtile + (size_t)t * (256 * 64);

    // V batch A (dg 0,1): issue BEFORE staging so counted vmcnt stays FIFO-safe
    half8 vA[8];
#pragma unroll
    for (int dg = 0; dg < 2; ++dg)
#pragma unroll
      for (int ks = 0; ks < 4; ++ks)
        vA[dg * 4 + ks] =
            *(const half8*)(vt_t + (size_t)(wk * 128 + dg * 32 + l31) * 64 + ks * 16 + h * 8);

    if (t + 1 < nt) {
      STAGEK(cur ^ 1, t + 1);
      asm volatile("s_waitcnt vmcnt(12)" ::: "memory");  // drain only K(t)'s 4
    } else {
      asm volatile("s_waitcnt vmcnt(8)" ::: "memory");
    }
    asm volatile("s_barrier" ::: "memory");  // A: K tile t ready

    const char* Ks = Kb + cur * 32768;
    const int k0 = t * 64;

    // S^T = K * Q^T
    f32x16 st;
#pragma unroll
    for (int r = 0; r < 16; ++r) st[r] = 0.f;
    if (!uni) {
      const int key = wk * 32 + l31;
      __builtin_amdgcn_s_setprio(1);
#pragma unroll
      for (int kt = 0; kt < 16; ++kt) {
        int byte = key * 512 + (((kt * 2 + h) ^ l31) << 4);
        half8 kf = *(const half8*)(Ks + byte);
        st = mfma32h(kf, qreg[kt], st);
      }
      __builtin_amdgcn_s_setprio(0);
      if (k0 + 64 > L) {
#pragma unroll
        for (int r = 0; r < 16; ++r) {
          int keyg = k0 + wk * 32 + (r & 3) + 8 * (r >> 2) + 4 * h;
          if (keyg >= L) st[r] = -1e6f;
        }
      }
    }

    // local softmax over own half (pair-combined)
    float pm = st[0];
#pragma unroll
    for (int r = 1; r < 16; ++r) pm = fmaxf(pm, st[r]);
    pm = fmaxf(pm, __shfl_xor(pm, 32));
    float psum = 0.f;
#pragma unroll
    for (int r = 0; r < 16; ++r) {
      float p_ = __expf(st[r] - pm);
      st[r] = p_;
      psum += p_;
    }
    psum += __shfl_xor(psum, 32);

    // publish P (local-max normalized) + (pm, psum)
#pragma unroll
    for (int i = 0; i < 8; ++i) {
      unsigned int pk = pkrtz(st[2 * i], st[2 * i + 1]);
      int kp = wk * 16 + 4 * (i >> 1) + (i & 1) + 2 * h;
      PL[wq * 1024 + kp * 32 + l31] = pk;
    }
    if (h == 0) {
      MLX[((wq * 2 + wk) * 2 + 0) * 32 + l31] = pm;
      MLX[((wq * 2 + wk) * 2 + 1) * 32 + l31] = psum;
    }

    // V batch B (dg 2,3) — in flight under barrier C + frag reads
    half8 vB[8];
#pragma unroll
    for (int dg = 0; dg < 2; ++dg)
#pragma unroll
      for (int ks = 0; ks < 4; ++ks)
        vB[dg * 4 + ks] =
            *(const half8*)(vt_t + (size_t)(wk * 128 + (dg + 2) * 32 + l31) * 64 + ks * 16 + h * 8);

    asm volatile("s_waitcnt lgkmcnt(0)\ns_barrier" ::: "memory");  // C

    // global m/l update from both halves
    float pm0 = MLX[((wq * 2 + 0) * 2 + 0) * 32 + l31];
    float ps0 = MLX[((wq * 2 + 0) * 2 + 1) * 32 + l31];
    float pm1 = MLX[((wq * 2 + 1) * 2 + 0) * 32 + l31];
    float ps1 = MLX[((wq * 2 + 1) * 2 + 1) * 32 + l31];
    float mnew = fmaxf(m, fmaxf(pm0, pm1));
    float scale = __expf(m - mnew);  // m=-inf -> 0
    m = mnew;
    float s0 = __expf(pm0 - mnew), s1 = __expf(pm1 - mnew);
    lsum = lsum * scale + s0 * ps0 + s1 * ps1;

    // read P frags; rescale halves by s0/s1 (packed fp16 muls)
    union { unsigned int u[4]; half8 v; } pf0, pf1, pf2, pf3;
#pragma unroll
    for (int w = 0; w < 4; ++w) {
      pf0.u[w] = PL[wq * 1024 + (0 * 8 + h * 4 + w) * 32 + l31];
      pf1.u[w] = PL[wq * 1024 + (1 * 8 + h * 4 + w) * 32 + l31];
      pf2.u[w] = PL[wq * 1024 + (2 * 8 + h * 4 + w) * 32 + l31];
      pf3.u[w] = PL[wq * 1024 + (3 * 8 + h * 4 + w) * 32 + l31];
    }
    {
      _Float16 s0h = (_Float16)s0, s1h = (_Float16)s1;
      half8 sc0 = {s0h, s0h, s0h, s0h, s0h, s0h, s0h, s0h};
      half8 sc1 = {s1h, s1h, s1h, s1h, s1h, s1h, s1h, s1h};
      pf0.v *= sc0;
      pf1.v *= sc0;
      pf2.v *= sc1;
      pf3.v *= sc1;
    }

    // rescale O^T
#pragma unroll
    for (int dg = 0; dg < 4; ++dg)
#pragma unroll
      for (int r = 0; r < 16; ++r) acc[dg][r] *= scale;

    // PV: O^T[d-half][32q] += V^T * P
    __builtin_amdgcn_s_setprio(1);
#pragma unroll
    for (int dg = 0; dg < 4; ++dg) {
      half8 v0 = (dg < 2) ? vA[dg * 4 + 0] : vB[(dg - 2) * 4 + 0];
      half8 v1 = (dg < 2) ? vA[dg * 4 + 1] : vB[(dg - 2) * 4 + 1];
      half8 v2 = (dg < 2) ? vA[dg * 4 + 2] : vB[(dg - 2) * 4 + 2];
      half8 v3 = (dg < 2) ? vA[dg * 4 + 3] : vB[(dg - 2) * 4 + 3];
      acc[dg] = mfma32h(v0, pf0.v, acc[dg]);
      acc[dg] = mfma32h(v1, pf1.v, acc[dg]);
      acc[dg] = mfma32h(v2, pf2.v, acc[dg]);
      acc[dg] = mfma32h(v3, pf3.v, acc[dg]);
    }
    __builtin_amdgcn_s_setprio(0);

    asm volatile("s_barrier" ::: "memory");  // D: protect K buf + PL/MLX
  }

  // ---- epilogue: 2-phase LDS transpose (64 q rows at a time) ----
  float linv = 1.f / lsum;
  float* T = (float*)SMEM;  // [64][260] f32 = 66560B
#pragma unroll
  for (int ph = 0; ph < 2; ++ph) {
    __syncthreads();
    if ((wq >> 1) == ph) {
      int ql = (wq & 1) * 32 + l31;
#pragma unroll
      for (int dg = 0; dg < 4; ++dg)
#pragma unroll
        for (int r = 0; r < 16; ++r) {
          int d = wk * 128 + dg * 32 + (r & 3) + 8 * (r >> 2) + 4 * h;
          T[ql * 260 + d] = acc[dg][r] * linv;
        }
    }
    __syncthreads();
    const int rb = tid >> 6, c4 = (tid & 63) * 4;
#pragma unroll
    for (int i = 0; i < 8; ++i) {
      int row = rb + i * 8;
      float4v v = *(const float4v*)(T + row * 260 + c4);
      *(float4v*)(out + ((size_t)b * Nn + q0 + ph * 64 + row) * Dd + c4) = v;
    }
  }
}

// ---------- launch ----------
extern "C" void kernel_launch(void* const* d_in, const int* in_sizes, int n_in,
                              void* d_out, int out_size, void* d_ws, size_t ws_size,
                              hipStream_t stream) {
  const float* x = (const float*)d_in[0];
  const int* vlen = (const int*)d_in[1];
  const float* Wq = (const float*)d_in[2];
  const float* bq = (const float*)d_in[3];
  const float* Wk = (const float*)d_in[4];
  const float* bk = (const float*)d_in[5];
  const float* Wv = (const float*)d_in[6];
  const float* bv = (const float*)d_in[7];
  float* out = (float*)d_out;
  char* ws = (char*)d_ws;

  _Float16* qh = (_Float16*)(ws);
  _Float16* kk = (_Float16*)(ws + 16777216);
  _Float16* vt = (_Float16*)(ws + 33554432);
  _Float16* wh = (_Float16*)(ws + 50331648);
  _Float16* xh = (_Float16*)d_out;  // scratch; fully overwritten by k_attn

  k_split_x<<<8192, 256, 0, stream>>>(x, xh);
  k_split_w<<<768, 256, 0, stream>>>(Wq, Wk, Wv, wh);
  k_qkv<<<dim3(256, 2, 3), 256, 0, stream>>>(xh, wh, bq, bk, bv, qh, kk, vt);
  k_attn<<<256, 512, 0, stream>>>(qh, kk, vt, vlen, out);
}

// Round 9
// 126.675 us; speedup vs baseline: 1.5990x; 1.5990x over previous
//
#include <hip/hip_runtime.h>
#include <hip/hip_bf16.h>
#include <stdint.h>

typedef __attribute__((ext_vector_type(8))) _Float16 half8;
typedef __attribute__((ext_vector_type(4))) _Float16 half4;
typedef __attribute__((ext_vector_type(2))) __fp16 fp16x2;
typedef __attribute__((ext_vector_type(4))) float f32x4;
typedef __attribute__((ext_vector_type(16))) float f32x16;
typedef __attribute__((ext_vector_type(4))) float float4v;

#define DEVI static __device__ __forceinline__

constexpr int Bb = 16, Nn = 2048, Cc = 256, Dd = 256;

DEVI unsigned short f2h_bits(float f) {
  _Float16 h = (_Float16)f;
  union { _Float16 h; unsigned short u; } c;
  c.h = h;
  return c.u;
}

DEVI void gl_lds16(const void* gsrc, void* ldst) {
  __builtin_amdgcn_global_load_lds(
      (const __attribute__((address_space(1))) unsigned int*)gsrc,
      (__attribute__((address_space(3))) unsigned int*)ldst, 16, 0, 0);
}

DEVI f32x4 mfma16h(half8 a, half8 b, f32x4 c) {
  return __builtin_amdgcn_mfma_f32_16x16x32_f16(a, b, c, 0, 0, 0);
}
DEVI f32x16 mfma32h(half8 a, half8 b, f32x16 c) {
  return __builtin_amdgcn_mfma_f32_32x32x16_f16(a, b, c, 0, 0, 0);
}

DEVI unsigned int pkrtz(float a, float b) {
  union { fp16x2 h; unsigned int u; } c;
  c.h = __builtin_amdgcn_cvt_pkrtz(a, b);
  return c.u;
}

// ---------- kernel 0a: x (f32) -> xh (fp16) ----------
__global__ void k_split_x(const float* __restrict__ x, _Float16* __restrict__ xh) {
  int i = blockIdx.x * 256 + threadIdx.x;
  float4v v = reinterpret_cast<const float4v*>(x)[i];
  half4 h;
#pragma unroll
  for (int j = 0; j < 4; ++j) h[j] = (_Float16)v[j];
  reinterpret_cast<half4*>(xh)[i] = h;
}

// ---------- kernel 0b: W (f32) -> wh (fp16), [mat][d][c] ----------
__global__ void k_split_w(const float* __restrict__ wq, const float* __restrict__ wk,
                          const float* __restrict__ wv, _Float16* __restrict__ wh) {
  int i = blockIdx.x * 256 + threadIdx.x;
  int mat = i >> 16;
  int rem = i & 65535;
  const float* w = (mat == 0) ? wq : ((mat == 1) ? wk : wv);
  wh[(size_t)mat * 65536 + rem] = (_Float16)w[rem];
}

// ---------- kernel 1: QKV projection GEMM (fp16 in, f32 acc) ----------
__global__ __launch_bounds__(256, 2) void k_qkv(
    const _Float16* __restrict__ xh, const _Float16* __restrict__ wh,
    const float* __restrict__ bq, const float* __restrict__ bk, const float* __restrict__ bv,
    _Float16* __restrict__ qout, _Float16* __restrict__ kout, _Float16* __restrict__ vt) {
  __shared__ __align__(16) unsigned short smem[17408];

  const int tid = threadIdx.x;
  const int m0 = blockIdx.x * 128;
  const int n0 = blockIdx.y * 128;
  const int mat = blockIdx.z;
  const _Float16* wmat = wh + (size_t)mat * 65536;
  const int wave = tid >> 6, lane = tid & 63;
  const int wr = wave >> 1, wc = wave & 1;
  const int l15 = lane & 15, lq = lane >> 4;

  f32x4 zero4 = {0.f, 0.f, 0.f, 0.f};
  f32x4 acc[4][4];
#pragma unroll
  for (int a = 0; a < 4; ++a)
#pragma unroll
    for (int b2 = 0; b2 < 4; ++b2) acc[a][b2] = zero4;

  char* As = (char*)smem;
  char* Bs = (char*)smem + 16384;

  for (int kc = 0; kc < 4; ++kc) {
#pragma unroll
    for (int i = 0; i < 4; ++i) {
      int p = i * 4096 + tid * 16;
      int row = p >> 7;
      int src_in_row = (p & 127) ^ ((row & 7) << 4);
      const char* g = (const char*)(xh + (size_t)(m0 + row) * Cc + kc * 64) + src_in_row;
      gl_lds16(g, As + p);
    }
#pragma unroll
    for (int i = 0; i < 4; ++i) {
      int p = i * 4096 + tid * 16;
      int row = p >> 7;
      int src_in_row = (p & 127) ^ ((row & 7) << 4);
      const char* g = (const char*)(wmat + (size_t)(n0 + row) * Cc + kc * 64) + src_in_row;
      gl_lds16(g, Bs + p);
    }
    __syncthreads();
#pragma unroll
    for (int ks = 0; ks < 2; ++ks) {
      half8 af[4], bfr[4];
#pragma unroll
      for (int mf = 0; mf < 4; ++mf) {
        int row = wr * 64 + mf * 16 + l15;
        int byte = (row * 128 + ks * 64 + lq * 16) ^ ((row & 7) << 4);
        af[mf] = *(const half8*)(As + byte);
      }
#pragma unroll
      for (int nf = 0; nf < 4; ++nf) {
        int row = wc * 64 + nf * 16 + l15;
        int byte = (row * 128 + ks * 64 + lq * 16) ^ ((row & 7) << 4);
        bfr[nf] = *(const half8*)(Bs + byte);
      }
#pragma unroll
      for (int mf = 0; mf < 4; ++mf)
#pragma unroll
        for (int nf = 0; nf < 4; ++nf) acc[mf][nf] = mfma16h(af[mf], bfr[nf], acc[mf][nf]);
    }
    __syncthreads();
  }

  const float* bias = (mat == 0) ? bq : ((mat == 1) ? bk : bv);
  if (mat < 2) {
    _Float16* oo = (mat == 0) ? qout : kout;
#pragma unroll
    for (int nf = 0; nf < 4; ++nf) {
      int col = n0 + wc * 64 + nf * 16 + l15;
      float bval = bias[col];
#pragma unroll
      for (int mf = 0; mf < 4; ++mf) {
        int grow = m0 + wr * 64 + mf * 16 + lq * 4;
#pragma unroll
        for (int r = 0; r < 4; ++r)
          oo[(size_t)(grow + r) * Dd + col] = (_Float16)(acc[mf][nf][r] + bval);
      }
    }
  } else {
    // V: transpose tile through LDS -> coalesced stores into vt[B][D][N]
    __syncthreads();
#pragma unroll
    for (int nf = 0; nf < 4; ++nf) {
      int dl = wc * 64 + nf * 16 + l15;
      float bval = bias[n0 + dl];
#pragma unroll
      for (int mf = 0; mf < 4; ++mf) {
        int nl = wr * 64 + mf * 16 + lq * 4;
#pragma unroll
        for (int r = 0; r < 4; ++r) smem[dl * 136 + nl + r] = f2h_bits(acc[mf][nf][r] + bval);
      }
    }
    __syncthreads();
    const int bbat = m0 >> 11, tok0 = m0 & 2047;
#pragma unroll
    for (int pss = 0; pss < 8; ++pss) {
      int idx = pss * 256 + tid;
      int dl = idx >> 4;
      int cu = idx & 15;
      half8 vval = *(const half8*)((const char*)smem + dl * 272 + cu * 16);
      size_t off = ((size_t)bbat * Dd + n0 + dl) * Nn + tok0 + cu * 8;
      *(half8*)(vt + off) = vval;
    }
  }
}

// ---------- kernel 2: flash attention, 8 waves = 4 wq x 2 wk ----------
// Round-7 structure (K+V LDS dbuf, counted vmcnt) + merged softmax exchange
// (3 barriers/tile), QK split into 2 MFMA chains, V-frag prefetch for dg 0,1.
__global__ __launch_bounds__(512, 2) void k_attn(
    const _Float16* __restrict__ qg, const _Float16* __restrict__ kin,
    const _Float16* __restrict__ vt, const int* __restrict__ vlen,
    float* __restrict__ out) {
  __shared__ __align__(16) char SMEM[149504];
  char* const KVb = SMEM;                                   // [2][65536]: K 32KB | V 32KB
  unsigned int* const PL = (unsigned int*)(SMEM + 131072);  // [4 wq][32 kp][32 q]
  float* const MLX = (float*)(SMEM + 147456);               // [4 wq][2 wk][2][32]

  const int tid = threadIdx.x;
  const int wave = tid >> 6, lane = tid & 63;
  const int l31 = lane & 31, h = lane >> 5;
  const int wq = wave >> 1, wk = wave & 1;
  const int id = blockIdx.x;
  const int g = id & 7;
  const int j = id >> 3;
  const int b = g + 8 * (j >> 4);  // XCD g owns batches {g, g+8}
  const int q0 = (j & 15) * 128;
  const int L = vlen[b];
  const bool uni = (L == 0);
  const int Lk = uni ? Nn : L;
  const int nt = (Lk + 63) >> 6;

  const char* kbase = (const char*)(kin + (size_t)b * Nn * Dd);
  const char* vbase = (const char*)(vt + (size_t)b * Dd * Nn);
  const char* qbase = (const char*)(qg + ((size_t)b * Nn + q0) * Dd);

  // K LDS: [64 key][512B], 5-bit XOR slot swizzle. V LDS: d-quad interleaved.
  auto STAGE = [&](int buf, int t) {
    char* dst = KVb + buf * 65536;
    const int k0 = t * 64;
#pragma unroll
    for (int i = 0; i < 4; ++i) {
      int p = i * 8192 + tid * 16;
      int row = p >> 9;
      int sl = ((p & 511) >> 4) ^ (row & 31);
      gl_lds16(kbase + (size_t)(k0 + row) * 512 + (sl << 4), dst + p);
    }
#pragma unroll
    for (int i = 0; i < 4; ++i) {
      int p = i * 8192 + tid * 16;
      int r = p >> 9;
      int sl = ((p & 511) >> 4) ^ (r & 31);
      int cl = sl << 4;
      int d = r * 4 + (cl >> 7);
      int kbyte = cl & 127;
      gl_lds16(vbase + (size_t)d * (Nn * 2) + (size_t)k0 * 2 + kbyte, dst + 32768 + p);
    }
  };

  // prologue: stage tile 0 into buf0, Q tile into buf1 (K-style layout)
  STAGE(0, 0);
#pragma unroll
  for (int i = 0; i < 8; ++i) {
    int p = i * 8192 + tid * 16;
    int row = p >> 9;
    int sl = ((p & 511) >> 4) ^ (row & 31);
    gl_lds16(qbase + (size_t)row * 512 + (sl << 4), KVb + 65536 + p);
  }
  asm volatile("s_waitcnt vmcnt(0)" ::: "memory");
  asm volatile("s_barrier" ::: "memory");

  half8 qreg[16];
  {
    const int row = wq * 32 + l31;
#pragma unroll
    for (int kt = 0; kt < 16; ++kt) {
      int byte = row * 512 + (((kt * 2 + h) ^ (row & 31)) << 4);
      qreg[kt] = *(const half8*)(KVb + 65536 + byte);
    }
  }
  asm volatile("s_waitcnt lgkmcnt(0)" ::: "memory");
  asm volatile("s_barrier" ::: "memory");  // protect buf1 before loop staging

  f32x16 acc[4];
#pragma unroll
  for (int dg = 0; dg < 4; ++dg)
#pragma unroll
    for (int r = 0; r < 16; ++r) acc[dg][r] = 0.f;
  float m = -__builtin_inff();
  float lsum = 0.f;

  for (int t = 0; t < nt; ++t) {
    const int cur = t & 1;
    if (t + 1 < nt) {
      STAGE(cur ^ 1, t + 1);
      asm volatile("s_waitcnt vmcnt(8)" ::: "memory");  // drain only tile t's 8
    } else {
      asm volatile("s_waitcnt vmcnt(0)" ::: "memory");
    }
    asm volatile("s_barrier" ::: "memory");  // A: tile t ready

    const char* Ks = KVb + cur * 65536;
    const char* Vs = Ks + 32768;
    const int k0 = t * 64;

    // S^T = K * Q^T : two independent MFMA chains (halved dependency depth)
    f32x16 st;
    if (!uni) {
      const int key = wk * 32 + l31;
      f32x16 e0, e1;
#pragma unroll
      for (int r = 0; r < 16; ++r) {
        e0[r] = 0.f;
        e1[r] = 0.f;
      }
      __builtin_amdgcn_s_setprio(1);
#pragma unroll
      for (int kt = 0; kt < 16; kt += 2) {
        int byteA = key * 512 + (((kt * 2 + h) ^ l31) << 4);
        int byteB = key * 512 + ((((kt + 1) * 2 + h) ^ l31) << 4);
        half8 kfA = *(const half8*)(Ks + byteA);
        half8 kfB = *(const half8*)(Ks + byteB);
        e0 = mfma32h(kfA, qreg[kt], e0);
        e1 = mfma32h(kfB, qreg[kt + 1], e1);
      }
      __builtin_amdgcn_s_setprio(0);
      st = e0 + e1;
      if (k0 + 64 > L) {
#pragma unroll
        for (int r = 0; r < 16; ++r) {
          int keyg = k0 + wk * 32 + (r & 3) + 8 * (r >> 2) + 4 * h;
          if (keyg >= L) st[r] = -1e6f;
        }
      }
    } else {
#pragma unroll
      for (int r = 0; r < 16; ++r) st[r] = 0.f;
    }

    // V-frag prefetch for dg 0,1 (buffer stable until barrier D) — latency
    // hides under the softmax VALU phase below.
    half8 vA[8];
#pragma unroll
    for (int dg = 0; dg < 2; ++dg) {
      int r = wk * 32 + dg * 8 + (l31 >> 2);
#pragma unroll
      for (int ks = 0; ks < 4; ++ks) {
        int slot = (l31 & 3) * 8 + ks * 2 + h;
        vA[dg * 4 + ks] = *(const half8*)(Vs + r * 512 + ((slot ^ (r & 31)) << 4));
      }
    }

    // local softmax over own half (pair-combined)
    float pm = st[0];
#pragma unroll
    for (int r = 1; r < 16; ++r) pm = fmaxf(pm, st[r]);
    pm = fmaxf(pm, __shfl_xor(pm, 32));
    float psum = 0.f;
#pragma unroll
    for (int r = 0; r < 16; ++r) {
      float p_ = __expf(st[r] - pm);
      st[r] = p_;
      psum += p_;
    }
    psum += __shfl_xor(psum, 32);

    // publish P (local-max normalized) + (pm, psum) in ONE exchange
#pragma unroll
    for (int i = 0; i < 8; ++i) {
      unsigned int pk = pkrtz(st[2 * i], st[2 * i + 1]);
      int kp = wk * 16 + 4 * (i >> 1) + (i & 1) + 2 * h;
      PL[wq * 1024 + kp * 32 + l31] = pk;
    }
    if (h == 0) {
      MLX[((wq * 2 + wk) * 2 + 0) * 32 + l31] = pm;
      MLX[((wq * 2 + wk) * 2 + 1) * 32 + l31] = psum;
    }
    asm volatile("s_waitcnt lgkmcnt(0)\ns_barrier" ::: "memory");  // C

    // global m/l update from both halves
    float pm0 = MLX[((wq * 2 + 0) * 2 + 0) * 32 + l31];
    float ps0 = MLX[((wq * 2 + 0) * 2 + 1) * 32 + l31];
    float pm1 = MLX[((wq * 2 + 1) * 2 + 0) * 32 + l31];
    float ps1 = MLX[((wq * 2 + 1) * 2 + 1) * 32 + l31];
    float mnew = fmaxf(m, fmaxf(pm0, pm1));
    float scale = __expf(m - mnew);  // m=-inf -> 0
    m = mnew;
    float s0 = __expf(pm0 - mnew), s1 = __expf(pm1 - mnew);
    lsum = lsum * scale + s0 * ps0 + s1 * ps1;

    // read P frags; rescale halves by s0/s1 (packed fp16 muls)
    union { unsigned int u[4]; half8 v; } pf0, pf1, pf2, pf3;
#pragma unroll
    for (int w = 0; w < 4; ++w) {
      pf0.u[w] = PL[wq * 1024 + (0 * 8 + h * 4 + w) * 32 + l31];
      pf1.u[w] = PL[wq * 1024 + (1 * 8 + h * 4 + w) * 32 + l31];
      pf2.u[w] = PL[wq * 1024 + (2 * 8 + h * 4 + w) * 32 + l31];
      pf3.u[w] = PL[wq * 1024 + (3 * 8 + h * 4 + w) * 32 + l31];
    }
    {
      _Float16 s0h = (_Float16)s0, s1h = (_Float16)s1;
      half8 sc0 = {s0h, s0h, s0h, s0h, s0h, s0h, s0h, s0h};
      half8 sc1 = {s1h, s1h, s1h, s1h, s1h, s1h, s1h, s1h};
      pf0.v *= sc0;
      pf1.v *= sc0;
      pf2.v *= sc1;
      pf3.v *= sc1;
    }

    // rescale O^T (lane-local)
#pragma unroll
    for (int dg = 0; dg < 4; ++dg)
#pragma unroll
      for (int r = 0; r < 16; ++r) acc[dg][r] *= scale;

    // PV: O^T[d-half][32q] += V^T * P  (dg 0,1 prefetched; dg 2,3 read here)
    __builtin_amdgcn_s_setprio(1);
#pragma unroll
    for (int dg = 0; dg < 4; ++dg) {
      half8 v0, v1, v2, v3;
      if (dg < 2) {
        v0 = vA[dg * 4 + 0];
        v1 = vA[dg * 4 + 1];
        v2 = vA[dg * 4 + 2];
        v3 = vA[dg * 4 + 3];
      } else {
        int r = wk * 32 + dg * 8 + (l31 >> 2);
        int s0l = (l31 & 3) * 8 + 0 * 2 + h;
        int s1l = (l31 & 3) * 8 + 1 * 2 + h;
        int s2l = (l31 & 3) * 8 + 2 * 2 + h;
        int s3l = (l31 & 3) * 8 + 3 * 2 + h;
        v0 = *(const half8*)(Vs + r * 512 + ((s0l ^ (r & 31)) << 4));
        v1 = *(const half8*)(Vs + r * 512 + ((s1l ^ (r & 31)) << 4));
        v2 = *(const half8*)(Vs + r * 512 + ((s2l ^ (r & 31)) << 4));
        v3 = *(const half8*)(Vs + r * 512 + ((s3l ^ (r & 31)) << 4));
      }
      acc[dg] = mfma32h(v0, pf0.v, acc[dg]);
      acc[dg] = mfma32h(v1, pf1.v, acc[dg]);
      acc[dg] = mfma32h(v2, pf2.v, acc[dg]);
      acc[dg] = mfma32h(v3, pf3.v, acc[dg]);
    }
    __builtin_amdgcn_s_setprio(0);

    asm volatile("s_barrier" ::: "memory");  // D: protect KV[cur] + PL/MLX
  }

  // ---- epilogue ----
  float linv = 1.f / lsum;

  // transpose through LDS: T[q 128][260 f32] (reuses KV+PL region)
  float* T = (float*)SMEM;
  {
    const int ql = wq * 32 + l31;
#pragma unroll
    for (int dg = 0; dg < 4; ++dg)
#pragma unroll
      for (int r = 0; r < 16; ++r) {
        int d = wk * 128 + dg * 32 + (r & 3) + 8 * (r >> 2) + 4 * h;
        T[ql * 260 + d] = acc[dg][r] * linv;
      }
  }
  asm volatile("s_waitcnt lgkmcnt(0)\ns_barrier" ::: "memory");

  // coalesced stores: 64 lanes cover 1KB of one row per instruction
  {
    const int rb = tid >> 6;        // 0..7
    const int c4 = (tid & 63) * 4;  // float offset
#pragma unroll
    for (int i = 0; i < 16; ++i) {
      int row = rb + i * 8;
      float4v v = *(const float4v*)(T + row * 260 + c4);
      *(float4v*)(out + ((size_t)b * Nn + q0 + row) * Dd + c4) = v;
    }
  }
}

// ---------- launch ----------
extern "C" void kernel_launch(void* const* d_in, const int* in_sizes, int n_in,
                              void* d_out, int out_size, void* d_ws, size_t ws_size,
                              hipStream_t stream) {
  const float* x = (const float*)d_in[0];
  const int* vlen = (const int*)d_in[1];
  const float* Wq = (const float*)d_in[2];
  const float* bq = (const float*)d_in[3];
  const float* Wk = (const float*)d_in[4];
  const float* bk = (const float*)d_in[5];
  const float* Wv = (const float*)d_in[6];
  const float* bv = (const float*)d_in[7];
  float* out = (float*)d_out;
  char* ws = (char*)d_ws;

  _Float16* qh = (_Float16*)(ws);
  _Float16* kk = (_Float16*)(ws + 16777216);
  _Float16* vt = (_Float16*)(ws + 33554432);
  _Float16* wh = (_Float16*)(ws + 50331648);
  _Float16* xh = (_Float16*)d_out;  // scratch; fully overwritten by k_attn

  k_split_x<<<8192, 256, 0, stream>>>(x, xh);
  k_split_w<<<768, 256, 0, stream>>>(Wq, Wk, Wv, wh);
  k_qkv<<<dim3(256, 2, 3), 256, 0, stream>>>(xh, wh, bq, bk, bv, qh, kk, vt);
  k_attn<<<256, 512, 0, stream>>>(qh, kk, vt, vlen, out);
}

// Round 10
// 122.179 us; speedup vs baseline: 1.6578x; 1.0368x over previous
//
#include <hip/hip_runtime.h>
#include <hip/hip_bf16.h>
#include <stdint.h>

typedef __attribute__((ext_vector_type(8))) _Float16 half8;
typedef __attribute__((ext_vector_type(4))) _Float16 half4;
typedef __attribute__((ext_vector_type(2))) __fp16 fp16x2;
typedef __attribute__((ext_vector_type(4))) float f32x4;
typedef __attribute__((ext_vector_type(16))) float f32x16;
typedef __attribute__((ext_vector_type(4))) float float4v;

#define DEVI static __device__ __forceinline__

constexpr int Bb = 16, Nn = 2048, Cc = 256, Dd = 256;

DEVI unsigned short f2h_bits(float f) {
  _Float16 h = (_Float16)f;
  union { _Float16 h; unsigned short u; } c;
  c.h = h;
  return c.u;
}

DEVI void gl_lds16(const void* gsrc, void* ldst) {
  __builtin_amdgcn_global_load_lds(
      (const __attribute__((address_space(1))) unsigned int*)gsrc,
      (__attribute__((address_space(3))) unsigned int*)ldst, 16, 0, 0);
}

DEVI f32x4 mfma16h(half8 a, half8 b, f32x4 c) {
  return __builtin_amdgcn_mfma_f32_16x16x32_f16(a, b, c, 0, 0, 0);
}
DEVI f32x16 mfma32h(half8 a, half8 b, f32x16 c) {
  return __builtin_amdgcn_mfma_f32_32x32x16_f16(a, b, c, 0, 0, 0);
}

DEVI unsigned int pkrtz(float a, float b) {
  union { fp16x2 h; unsigned int u; } c;
  c.h = __builtin_amdgcn_cvt_pkrtz(a, b);
  return c.u;
}

// ---------- kernel 0: fused x->fp16 and W->fp16 split ----------
__global__ void k_split(const float* __restrict__ x, const float* __restrict__ wq,
                        const float* __restrict__ wk, const float* __restrict__ wv,
                        _Float16* __restrict__ xh, _Float16* __restrict__ wh) {
  int i = blockIdx.x * 256 + threadIdx.x;
  if (i < 2097152) {  // x: 4 floats per thread
    float4v v = reinterpret_cast<const float4v*>(x)[i];
    half4 h;
#pragma unroll
    for (int j = 0; j < 4; ++j) h[j] = (_Float16)v[j];
    reinterpret_cast<half4*>(xh)[i] = h;
  } else {  // W: 1 float per thread (196608 total)
    int ii = i - 2097152;
    int mat = ii >> 16;
    int rem = ii & 65535;
    const float* w = (mat == 0) ? wq : ((mat == 1) ? wk : wv);
    wh[(size_t)mat * 65536 + rem] = (_Float16)w[rem];
  }
}

// ---------- kernel 1: QKV projection GEMM (fp16 in, f32 acc) ----------
__global__ __launch_bounds__(256, 2) void k_qkv(
    const _Float16* __restrict__ xh, const _Float16* __restrict__ wh,
    const float* __restrict__ bq, const float* __restrict__ bk, const float* __restrict__ bv,
    _Float16* __restrict__ qout, _Float16* __restrict__ kout, _Float16* __restrict__ vt) {
  __shared__ __align__(16) unsigned short smem[17408];

  const int tid = threadIdx.x;
  const int m0 = blockIdx.x * 128;
  const int n0 = blockIdx.y * 128;
  const int mat = blockIdx.z;
  const _Float16* wmat = wh + (size_t)mat * 65536;
  const int wave = tid >> 6, lane = tid & 63;
  const int wr = wave >> 1, wc = wave & 1;
  const int l15 = lane & 15, lq = lane >> 4;

  f32x4 zero4 = {0.f, 0.f, 0.f, 0.f};
  f32x4 acc[4][4];
#pragma unroll
  for (int a = 0; a < 4; ++a)
#pragma unroll
    for (int b2 = 0; b2 < 4; ++b2) acc[a][b2] = zero4;

  char* As = (char*)smem;
  char* Bs = (char*)smem + 16384;

  for (int kc = 0; kc < 4; ++kc) {
#pragma unroll
    for (int i = 0; i < 4; ++i) {
      int p = i * 4096 + tid * 16;
      int row = p >> 7;
      int src_in_row = (p & 127) ^ ((row & 7) << 4);
      const char* g = (const char*)(xh + (size_t)(m0 + row) * Cc + kc * 64) + src_in_row;
      gl_lds16(g, As + p);
    }
#pragma unroll
    for (int i = 0; i < 4; ++i) {
      int p = i * 4096 + tid * 16;
      int row = p >> 7;
      int src_in_row = (p & 127) ^ ((row & 7) << 4);
      const char* g = (const char*)(wmat + (size_t)(n0 + row) * Cc + kc * 64) + src_in_row;
      gl_lds16(g, Bs + p);
    }
    __syncthreads();
#pragma unroll
    for (int ks = 0; ks < 2; ++ks) {
      half8 af[4], bfr[4];
#pragma unroll
      for (int mf = 0; mf < 4; ++mf) {
        int row = wr * 64 + mf * 16 + l15;
        int byte = (row * 128 + ks * 64 + lq * 16) ^ ((row & 7) << 4);
        af[mf] = *(const half8*)(As + byte);
      }
#pragma unroll
      for (int nf = 0; nf < 4; ++nf) {
        int row = wc * 64 + nf * 16 + l15;
        int byte = (row * 128 + ks * 64 + lq * 16) ^ ((row & 7) << 4);
        bfr[nf] = *(const half8*)(Bs + byte);
      }
#pragma unroll
      for (int mf = 0; mf < 4; ++mf)
#pragma unroll
        for (int nf = 0; nf < 4; ++nf) acc[mf][nf] = mfma16h(af[mf], bfr[nf], acc[mf][nf]);
    }
    __syncthreads();
  }

  const float* bias = (mat == 0) ? bq : ((mat == 1) ? bk : bv);
  if (mat < 2) {
    _Float16* oo = (mat == 0) ? qout : kout;
#pragma unroll
    for (int nf = 0; nf < 4; ++nf) {
      int col = n0 + wc * 64 + nf * 16 + l15;
      float bval = bias[col];
#pragma unroll
      for (int mf = 0; mf < 4; ++mf) {
        int grow = m0 + wr * 64 + mf * 16 + lq * 4;
#pragma unroll
        for (int r = 0; r < 4; ++r)
          oo[(size_t)(grow + r) * Dd + col] = (_Float16)(acc[mf][nf][r] + bval);
      }
    }
  } else {
    // V: transpose tile through LDS -> coalesced stores into vt[B][D][N]
    __syncthreads();
#pragma unroll
    for (int nf = 0; nf < 4; ++nf) {
      int dl = wc * 64 + nf * 16 + l15;
      float bval = bias[n0 + dl];
#pragma unroll
      for (int mf = 0; mf < 4; ++mf) {
        int nl = wr * 64 + mf * 16 + lq * 4;
#pragma unroll
        for (int r = 0; r < 4; ++r) smem[dl * 136 + nl + r] = f2h_bits(acc[mf][nf][r] + bval);
      }
    }
    __syncthreads();
    const int bbat = m0 >> 11, tok0 = m0 & 2047;
#pragma unroll
    for (int pss = 0; pss < 8; ++pss) {
      int idx = pss * 256 + tid;
      int dl = idx >> 4;
      int cu = idx & 15;
      half8 vval = *(const half8*)((const char*)smem + dl * 272 + cu * 16);
      size_t off = ((size_t)bbat * Dd + n0 + dl) * Nn + tok0 + cu * 8;
      *(half8*)(vt + off) = vval;
    }
  }
}

// ---------- kernel 2: flash attention, 8 waves = 4 wq x 2 wk ----------
// Round-7 structure (proven 93us): K+V LDS dbuf, counted vmcnt, 4 barriers.
// Edits: acc-rescale hoisted before barrier C (fills barrier wait, shortens
// post-C path to P-read -> PV) + __all(scale==1) skip guard (exact).
__global__ __launch_bounds__(512, 2) void k_attn(
    const _Float16* __restrict__ qg, const _Float16* __restrict__ kin,
    const _Float16* __restrict__ vt, const int* __restrict__ vlen,
    float* __restrict__ out) {
  __shared__ __align__(16) char SMEM[149504];
  char* const KVb = SMEM;                                   // [2][65536]: K 32KB | V 32KB
  unsigned int* const PL = (unsigned int*)(SMEM + 131072);  // [4 wq][32 kp][32 q]
  float* const mex = (float*)(SMEM + 147456);               // [8][32]
  float* const lex = (float*)(SMEM + 148480);               // [8][32]

  const int tid = threadIdx.x;
  const int wave = tid >> 6, lane = tid & 63;
  const int l31 = lane & 31, h = lane >> 5;
  const int wq = wave >> 1, wk = wave & 1;
  const int id = blockIdx.x;
  const int g = id & 7;
  const int j = id >> 3;
  const int b = g + 8 * (j >> 4);  // XCD g owns batches {g, g+8}
  const int q0 = (j & 15) * 128;
  const int L = vlen[b];
  const bool uni = (L == 0);
  const int Lk = uni ? Nn : L;
  const int nt = (Lk + 63) >> 6;

  const char* kbase = (const char*)(kin + (size_t)b * Nn * Dd);
  const char* vbase = (const char*)(vt + (size_t)b * Dd * Nn);
  const char* qbase = (const char*)(qg + ((size_t)b * Nn + q0) * Dd);

  // K LDS: [64 key][512B], 5-bit XOR slot swizzle. V LDS: d-quad interleaved.
  auto STAGE = [&](int buf, int t) {
    char* dst = KVb + buf * 65536;
    const int k0 = t * 64;
#pragma unroll
    for (int i = 0; i < 4; ++i) {
      int p = i * 8192 + tid * 16;
      int row = p >> 9;
      int sl = ((p & 511) >> 4) ^ (row & 31);
      gl_lds16(kbase + (size_t)(k0 + row) * 512 + (sl << 4), dst + p);
    }
#pragma unroll
    for (int i = 0; i < 4; ++i) {
      int p = i * 8192 + tid * 16;
      int r = p >> 9;
      int sl = ((p & 511) >> 4) ^ (r & 31);
      int cl = sl << 4;
      int d = r * 4 + (cl >> 7);
      int kbyte = cl & 127;
      gl_lds16(vbase + (size_t)d * (Nn * 2) + (size_t)k0 * 2 + kbyte, dst + 32768 + p);
    }
  };

  // prologue: stage tile 0 into buf0, Q tile into buf1 (K-style layout)
  STAGE(0, 0);
#pragma unroll
  for (int i = 0; i < 8; ++i) {
    int p = i * 8192 + tid * 16;
    int row = p >> 9;
    int sl = ((p & 511) >> 4) ^ (row & 31);
    gl_lds16(qbase + (size_t)row * 512 + (sl << 4), KVb + 65536 + p);
  }
  asm volatile("s_waitcnt vmcnt(0)" ::: "memory");
  asm volatile("s_barrier" ::: "memory");

  half8 qreg[16];
  {
    const int row = wq * 32 + l31;
#pragma unroll
    for (int kt = 0; kt < 16; ++kt) {
      int byte = row * 512 + (((kt * 2 + h) ^ (row & 31)) << 4);
      qreg[kt] = *(const half8*)(KVb + 65536 + byte);
    }
  }
  asm volatile("s_waitcnt lgkmcnt(0)" ::: "memory");
  asm volatile("s_barrier" ::: "memory");  // protect buf1 before loop staging

  f32x16 acc[4];
#pragma unroll
  for (int dg = 0; dg < 4; ++dg)
#pragma unroll
    for (int r = 0; r < 16; ++r) acc[dg][r] = 0.f;
  float m = -__builtin_inff();
  float lsum = 0.f;

  for (int t = 0; t < nt; ++t) {
    const int cur = t & 1;
    if (t + 1 < nt) {
      STAGE(cur ^ 1, t + 1);
      asm volatile("s_waitcnt vmcnt(8)" ::: "memory");  // drain only tile t's 8
    } else {
      asm volatile("s_waitcnt vmcnt(0)" ::: "memory");
    }
    asm volatile("s_barrier" ::: "memory");  // A: tile t ready

    const char* Ks = KVb + cur * 65536;
    const char* Vs = Ks + 32768;
    const int k0 = t * 64;

    // S^T = K * Q^T : A = K frag (LDS rows wk*32..), B = Q regs. col q = l31.
    f32x16 st;
#pragma unroll
    for (int r = 0; r < 16; ++r) st[r] = 0.f;
    if (!uni) {
      const int key = wk * 32 + l31;
      __builtin_amdgcn_s_setprio(1);
#pragma unroll
      for (int kt = 0; kt < 16; ++kt) {
        int byte = key * 512 + (((kt * 2 + h) ^ l31) << 4);
        half8 kf = *(const half8*)(Ks + byte);
        st = mfma32h(kf, qreg[kt], st);
      }
      __builtin_amdgcn_s_setprio(0);
      if (k0 + 64 > L) {
#pragma unroll
        for (int r = 0; r < 16; ++r) {
          int keyg = k0 + wk * 32 + (r & 3) + 8 * (r >> 2) + 4 * h;
          if (keyg >= L) st[r] = -1e6f;
        }
      }
    }

    // partial max over own 32 keys (rows + pair-lane)
    float pm = st[0];
#pragma unroll
    for (int r = 1; r < 16; ++r) pm = fmaxf(pm, st[r]);
    pm = fmaxf(pm, __shfl_xor(pm, 32));
    if (lane < 32) mex[wave * 32 + lane] = pm;
    asm volatile("s_waitcnt lgkmcnt(0)\ns_barrier" ::: "memory");  // B
    float pmo = mex[(wave ^ 1) * 32 + l31];
    float mnew = fmaxf(m, fmaxf(pm, pmo));
    float scale = __expf(m - mnew);  // m=-inf -> 0
    m = mnew;
    float psum = 0.f;
#pragma unroll
    for (int r = 0; r < 16; ++r) {
      float p_ = __expf(st[r] - mnew);
      st[r] = p_;
      psum += p_;
    }
    lsum = lsum * scale + psum;

    // pack P pairs -> PL[wq][kp][q]  (key(i) = wk*32 + 8*(i>>1) + 2*(i&1) + 4h)
#pragma unroll
    for (int i = 0; i < 8; ++i) {
      unsigned int pk = pkrtz(st[2 * i], st[2 * i + 1]);
      int kp = wk * 16 + 4 * (i >> 1) + (i & 1) + 2 * h;
      PL[wq * 1024 + kp * 32 + l31] = pk;
    }

    // rescale O^T hoisted here (fills barrier-C wait); skip when exact no-op
    if (!__all(scale == 1.0f)) {
#pragma unroll
      for (int dg = 0; dg < 4; ++dg)
#pragma unroll
        for (int r = 0; r < 16; ++r) acc[dg][r] *= scale;
    }

    asm volatile("s_waitcnt lgkmcnt(0)\ns_barrier" ::: "memory");  // C

    // read all-64-key P frags (B-operand: k = ks*16 + h*8 + j, col q = l31)
    union { unsigned int u[4]; half8 v; } pf0, pf1, pf2, pf3;
#pragma unroll
    for (int w = 0; w < 4; ++w) {
      pf0.u[w] = PL[wq * 1024 + (0 * 8 + h * 4 + w) * 32 + l31];
      pf1.u[w] = PL[wq * 1024 + (1 * 8 + h * 4 + w) * 32 + l31];
      pf2.u[w] = PL[wq * 1024 + (2 * 8 + h * 4 + w) * 32 + l31];
      pf3.u[w] = PL[wq * 1024 + (3 * 8 + h * 4 + w) * 32 + l31];
    }

    // PV: O^T[d-half][32q] += V^T * P. A-row d = wk*128 + dg*32 + l31.
    __builtin_amdgcn_s_setprio(1);
#pragma unroll
    for (int dg = 0; dg < 4; ++dg) {
      int r = wk * 32 + dg * 8 + (l31 >> 2);
#pragma unroll
      for (int ks = 0; ks < 4; ++ks) {
        int slot = (l31 & 3) * 8 + ks * 2 + h;
        half8 vf = *(const half8*)(Vs + r * 512 + ((slot ^ (r & 31)) << 4));
        acc[dg] = mfma32h(vf, ks == 0 ? pf0.v : (ks == 1 ? pf1.v : (ks == 2 ? pf2.v : pf3.v)),
                          acc[dg]);
      }
    }
    __builtin_amdgcn_s_setprio(0);

    asm volatile("s_barrier" ::: "memory");  // D: protect KV[cur] + PL
  }

  // ---- epilogue ----
  lsum += __shfl_xor(lsum, 32);
  if (lane < 32) lex[wave * 32 + lane] = lsum;
  asm volatile("s_waitcnt lgkmcnt(0)\ns_barrier" ::: "memory");
  float linv = 1.f / (lsum + lex[(wave ^ 1) * 32 + l31]);

  // transpose through LDS: T[q 128][260 f32] (reuses KV+PL region)
  float* T = (float*)SMEM;
  {
    const int ql = wq * 32 + l31;
#pragma unroll
    for (int dg = 0; dg < 4; ++dg)
#pragma unroll
      for (int r = 0; r < 16; ++r) {
        int d = wk * 128 + dg * 32 + (r & 3) + 8 * (r >> 2) + 4 * h;
        T[ql * 260 + d] = acc[dg][r] * linv;
      }
  }
  asm volatile("s_waitcnt lgkmcnt(0)\ns_barrier" ::: "memory");

  // coalesced stores: 64 lanes cover 1KB of one row per instruction
  {
    const int rb = tid >> 6;        // 0..7
    const int c4 = (tid & 63) * 4;  // float offset
#pragma unroll
    for (int i = 0; i < 16; ++i) {
      int row = rb + i * 8;
      float4v v = *(const float4v*)(T + row * 260 + c4);
      *(float4v*)(out + ((size_t)b * Nn + q0 + row) * Dd + c4) = v;
    }
  }
}

// ---------- launch ----------
extern "C" void kernel_launch(void* const* d_in, const int* in_sizes, int n_in,
                              void* d_out, int out_size, void* d_ws, size_t ws_size,
                              hipStream_t stream) {
  const float* x = (const float*)d_in[0];
  const int* vlen = (const int*)d_in[1];
  const float* Wq = (const float*)d_in[2];
  const float* bq = (const float*)d_in[3];
  const float* Wk = (const float*)d_in[4];
  const float* bk = (const float*)d_in[5];
  const float* Wv = (const float*)d_in[6];
  const float* bv = (const float*)d_in[7];
  float* out = (float*)d_out;
  char* ws = (char*)d_ws;

  _Float16* qh = (_Float16*)(ws);
  _Float16* kk = (_Float16*)(ws + 16777216);
  _Float16* vt = (_Float16*)(ws + 33554432);
  _Float16* wh = (_Float16*)(ws + 50331648);
  _Float16* xh = (_Float16*)d_out;  // scratch; fully overwritten by k_attn

  k_split<<<8960, 256, 0, stream>>>(x, Wq, Wk, Wv, xh, wh);
  k_qkv<<<dim3(256, 2, 3), 256, 0, stream>>>(xh, wh, bq, bk, bv, qh, kk, vt);
  k_attn<<<256, 512, 0, stream>>>(qh, kk, vt, vlen, out);
}